// Round 1
// baseline (1061.588 us; speedup 1.0000x reference)
//
#include <hip/hip_runtime.h>
#include <hip/hip_bf16.h>
#include <stdint.h>

#define BQ   32768
#define DD   1024
#define NHH  8
#define HH   128
#define EPSF 1e-6f
#define CAPF 15.0f

typedef unsigned short u16;
typedef short bf16x8 __attribute__((ext_vector_type(8)));
typedef float f32x4  __attribute__((ext_vector_type(4)));

__device__ __forceinline__ float bf2f(u16 v) {
  union { float f; unsigned u; } t; t.u = ((unsigned)v) << 16; return t.f;
}
__device__ __forceinline__ u16 f2bf(float f) {
  union { float f; unsigned u; } t; t.f = f;
  unsigned r = t.u + 0x7fffu + ((t.u >> 16) & 1u);
  return (u16)(r >> 16);
}

// async global->LDS, 16B per lane; LDS dest is wave-uniform base + lane*16
#define GLDS16(g, l) \
  __builtin_amdgcn_global_load_lds((const __attribute__((address_space(1))) unsigned int*)(g), \
                                   (__attribute__((address_space(3))) unsigned int*)(l), 16, 0, 0)

// ---------------------------------------------------------------------------
// 128x128 tile bf16 GEMM, C = A @ Bt^T  (A:[M,K], Bt:[N,K] row-major bf16)
// BK=64 (half the barrier drains of BK=32), XOR-swizzled LDS (2-way residual
// bank conflicts), XCD-chunked block swizzle.
// EPI 1: SiLU(x+bias) -> bf16     EPI 2: gating + per-head LN    EPI 3: fp32
// ---------------------------------------------------------------------------
template <int EPI>
__global__ __launch_bounds__(256, 2)
void gemm128(const u16* __restrict__ A, const u16* __restrict__ Bt,
             int M, int N, int K,
             const float* __restrict__ bias,
             u16* __restrict__ obf,
             const float* __restrict__ cin, const float* __restrict__ nin,
             const float* __restrict__ gI, const float* __restrict__ gF,
             const float* __restrict__ gO,
             const float* __restrict__ gnw, const float* __restrict__ gnb,
             float* __restrict__ cout, float* __restrict__ nout,
             float* __restrict__ of32)
{
  __shared__ __align__(16) u16 As[128 * 64];
  __shared__ __align__(16) u16 Bs[128 * 64];
  __shared__ float redS[2][128];
  __shared__ float redQ[2][128];
  __shared__ float sgI[128], sgF[128], sgO[128];

  const int t = threadIdx.x;
  const int w = t >> 6;          // wave 0..3
  const int l = t & 63;          // lane

  // XCD-aware chunked swizzle. Grid is always (8, 256) -> nwg = 2048, %8 == 0
  // so the simple bijective form is valid. Each XCD gets 256 contiguous work
  // ids = 32 A-panels; resident panels fit its private 4 MiB L2.
  const int orig = blockIdx.y * 8 + blockIdx.x;
  const int work = ((orig & 7) << 8) | (orig >> 3);
  const int m0 = (work >> 3) * 128;
  const int n0 = (work & 7) * 128;

  // staging (BK=64): each wave stages 32 rows of A and 32 of B per K-step,
  // 4 GLDS16 each. LDS row = 128B. Physical layout is linear (GLDS writes
  // base + lane*16); the LOGICAL position of physical byte o is
  // o ^ (((o>>7)&7)<<4)  (involution), realized by pre-swizzling the global
  // source column per lane:
  const int srow = (w << 5) + (l >> 3);            // 0..127
  const int scol = ((l & 7) ^ (l >> 3)) << 3;      // pre-swizzled granule
  const u16* gA = A + (size_t)(m0 + srow) * K + scol;
  const u16* gB = Bt + (size_t)(n0 + srow) * K + scol;
  u16* lA = As + (w << 11);   // wave-uniform base: 32 rows * 128B = 4KB
  u16* lB = Bs + (w << 11);

  f32x4 acc[4][4];
#pragma unroll
  for (int i = 0; i < 4; ++i)
#pragma unroll
    for (int j = 0; j < 4; ++j)
      acc[i][j] = (f32x4){0.f, 0.f, 0.f, 0.f};

  const int wm = w & 1, wn = w >> 1;       // 2x2 wave grid, 64x64 each
  const int q = l >> 4, lc = l & 15;
  const int arow = (wm * 64 + lc) * 64;    // fragment row base (elems)
  const int brow = (wn * 64 + lc) * 64;
  const int sx = (lc & 7) << 3;            // read-side XOR (elems, bits 3-5)

  for (int k0 = 0; k0 < K; k0 += 64) {
    __syncthreads();
#pragma unroll
    for (int i = 0; i < 4; ++i) {
      GLDS16(gA + (size_t)(8 * i) * K + k0, lA + i * 512);
      GLDS16(gB + (size_t)(8 * i) * K + k0, lB + i * 512);
    }
    __syncthreads();   // drains vmcnt before barrier -> LDS valid
#pragma unroll
    for (int kk = 0; kk < 2; ++kk) {
      bf16x8 af[4], bq[4];
      const int ko = ((kk << 5) | (q << 3)) ^ sx;
#pragma unroll
      for (int i = 0; i < 4; ++i) {
        af[i] = *(const bf16x8*)(As + arow + i * 1024 + ko);
        bq[i] = *(const bf16x8*)(Bs + brow + i * 1024 + ko);
      }
#pragma unroll
      for (int i = 0; i < 4; ++i)
#pragma unroll
        for (int j = 0; j < 4; ++j)
          acc[i][j] = __builtin_amdgcn_mfma_f32_16x16x32_bf16(af[i], bq[j], acc[i][j], 0, 0, 0);
    }
  }

  // C/D layout: col = n_base + lc, row = m_base + q*4 + r   (verified m89/m91)
  if constexpr (EPI == 1) {
#pragma unroll
    for (int i = 0; i < 4; ++i)
#pragma unroll
      for (int r = 0; r < 4; ++r) {
        size_t row = (size_t)(m0 + wm * 64 + i * 16 + q * 4 + r);
#pragma unroll
        for (int j = 0; j < 4; ++j) {
          int col = n0 + wn * 64 + j * 16 + lc;
          float v = acc[i][j][r] + bias[col];
          float s = v / (1.f + expf(-v));       // SiLU
          obf[row * (size_t)N + col] = f2bf(s);
        }
      }
  }

  if constexpr (EPI == 2) {
    const int head = n0 >> 7;                   // BN=128 == H: one head/block
    if (t < 128) {
      int rr = m0 + t;
      sgI[t] = gI[rr * NHH + head];
      sgF[t] = gF[rr * NHH + head];
      sgO[t] = gO[rr * NHH + head];
    }
    __syncthreads();
#pragma unroll
    for (int i = 0; i < 4; ++i)
#pragma unroll
      for (int r = 0; r < 4; ++r) {
        int rloc = wm * 64 + i * 16 + q * 4 + r;
        size_t grow = (size_t)(m0 + rloc) * (size_t)N;
        float fg = sgF[rloc], ig = sgI[rloc], og = sgO[rloc];
        float s = 0.f, ss = 0.f;
#pragma unroll
        for (int j = 0; j < 4; ++j) {
          int col = n0 + wn * 64 + j * 16 + lc;
          float z  = acc[i][j][r];
          float cv = fg * cin[grow + col] + ig * z;
          float nv = fg * nin[grow + col] + ig;
          cout[grow + col] = cv;
          nout[grow + col] = nv;
          float h = og * cv / (nv + EPSF);
          acc[i][j][r] = h;
          s += h; ss += h * h;
        }
        // reduce over the 16 lanes of this quad (covers wave's 64 cols)
#pragma unroll
        for (int mk = 1; mk < 16; mk <<= 1) {
          s  += __shfl_xor(s,  mk);
          ss += __shfl_xor(ss, mk);
        }
        if (lc == 0) { redS[wn][rloc] = s; redQ[wn][rloc] = ss; }
      }
    __syncthreads();
#pragma unroll
    for (int i = 0; i < 4; ++i)
#pragma unroll
      for (int r = 0; r < 4; ++r) {
        int rloc = wm * 64 + i * 16 + q * 4 + r;
        float s  = redS[0][rloc] + redS[1][rloc];
        float ss = redQ[0][rloc] + redQ[1][rloc];
        float mu  = s * (1.f / 128.f);
        float var = ss * (1.f / 128.f) - mu * mu;
        float rs  = rsqrtf(var + EPSF);
        size_t grow = (size_t)(m0 + rloc) * (size_t)N;
#pragma unroll
        for (int j = 0; j < 4; ++j) {
          int col = n0 + wn * 64 + j * 16 + lc;
          float hn = (acc[i][j][r] - mu) * rs * gnw[col] + gnb[col];
          obf[grow + col] = f2bf(hn);
        }
      }
  }

  if constexpr (EPI == 3) {
#pragma unroll
    for (int i = 0; i < 4; ++i)
#pragma unroll
      for (int r = 0; r < 4; ++r) {
        size_t row = (size_t)(m0 + wm * 64 + i * 16 + q * 4 + r);
#pragma unroll
        for (int j = 0; j < 4; ++j) {
          int col = n0 + wn * 64 + j * 16 + lc;
          of32[row * (size_t)N + col] = acc[i][j][r];
        }
      }
  }
}

// ---------------------------------------------------------------------------
// Gates: one wave per batch row. i/f from x_conv, o from x; softcap + stable
// exp gating. Writes i_g/f_g/o_g to ws, m_new to d_out.
// ---------------------------------------------------------------------------
__global__ __launch_bounds__(256)
void gates_k(const u16* __restrict__ xbf, const u16* __restrict__ xcbf,
             const u16* __restrict__ wi, const u16* __restrict__ wf,
             const u16* __restrict__ wo,
             const float* __restrict__ ib, const float* __restrict__ fb,
             const float* __restrict__ ob, const float* __restrict__ min_,
             float* __restrict__ gI, float* __restrict__ gF,
             float* __restrict__ gO, float* __restrict__ mout)
{
  const int w = threadIdx.x >> 6, l = threadIdx.x & 63;
  const int row = blockIdx.x * 4 + w;
  const u16* xr  = xbf  + (size_t)row * DD;
  const u16* xcr = xcbf + (size_t)row * DD;
  bf16x8 xa = *(const bf16x8*)(xr + l * 8);
  bf16x8 xb = *(const bf16x8*)(xr + 512 + l * 8);
  bf16x8 ca = *(const bf16x8*)(xcr + l * 8);
  bf16x8 cb = *(const bf16x8*)(xcr + 512 + l * 8);
  float xf[16], cf[16];
#pragma unroll
  for (int j = 0; j < 8; ++j) {
    xf[j] = bf2f((u16)xa[j]); xf[8 + j] = bf2f((u16)xb[j]);
    cf[j] = bf2f((u16)ca[j]); cf[8 + j] = bf2f((u16)cb[j]);
  }
#pragma unroll
  for (int h = 0; h < NHH; ++h) {
    const u16* wip = wi + h * DD;
    const u16* wfp = wf + h * DD;
    const u16* wop = wo + h * DD;
    bf16x8 wia = *(const bf16x8*)(wip + l * 8), wib = *(const bf16x8*)(wip + 512 + l * 8);
    bf16x8 wfa = *(const bf16x8*)(wfp + l * 8), wfb = *(const bf16x8*)(wfp + 512 + l * 8);
    bf16x8 woa = *(const bf16x8*)(wop + l * 8), wob = *(const bf16x8*)(wop + 512 + l * 8);
    float si = 0.f, sf = 0.f, so = 0.f;
#pragma unroll
    for (int j = 0; j < 8; ++j) {
      si += cf[j] * bf2f((u16)wia[j]) + cf[8 + j] * bf2f((u16)wib[j]);
      sf += cf[j] * bf2f((u16)wfa[j]) + cf[8 + j] * bf2f((u16)wfb[j]);
      so += xf[j] * bf2f((u16)woa[j]) + xf[8 + j] * bf2f((u16)wob[j]);
    }
#pragma unroll
    for (int mk = 1; mk < 64; mk <<= 1) {
      si += __shfl_xor(si, mk);
      sf += __shfl_xor(sf, mk);
      so += __shfl_xor(so, mk);
    }
    if (l == 0) {
      float it = CAPF * tanhf((si + ib[h]) / CAPF);
      float ft = CAPF * tanhf((sf + fb[h]) / CAPF);
      float ot = CAPF * tanhf((so + ob[h]) / CAPF);
      float flog = -log1pf(expf(-ft));            // log(sigmoid(f_t))
      float mo = min_[(size_t)row * NHH + h];
      float mn = fmaxf(flog + mo, it);
      size_t o = (size_t)row * NHH + h;
      gI[o] = expf(it - mn);
      gF[o] = expf(flog + mo - mn);
      gO[o] = 1.f / (1.f + expf(-ot));
      mout[o] = mn;
    }
  }
}

// ---------------------------------------------------------------------------
__global__ __launch_bounds__(256)
void cvt_f2b(const float* __restrict__ in, u16* __restrict__ out, int n4) {
  int i = blockIdx.x * 256 + threadIdx.x;
  if (i >= n4) return;
  float4 v = ((const float4*)in)[i];
  ushort4 o;
  o.x = f2bf(v.x); o.y = f2bf(v.y); o.z = f2bf(v.z); o.w = f2bf(v.w);
  ((ushort4*)out)[i] = o;
}

// w1[o,i] = conv_w[o, i, K-1]  (K=4), coalesced float4 gather
__global__ __launch_bounds__(256)
void cvt_conv(const float* __restrict__ cw, u16* __restrict__ w1) {
  int e = blockIdx.x * 256 + threadIdx.x;   // e < DD*DD
  float4 v = ((const float4*)cw)[e];
  w1[e] = f2bf(v.w);
}

// ---------------------------------------------------------------------------
extern "C" void kernel_launch(void* const* d_in, const int* in_sizes, int n_in,
                              void* d_out, int out_size, void* d_ws, size_t ws_size,
                              hipStream_t stream) {
  const float* x_in   = (const float*)d_in[0];
  const float* cst_in = (const float*)d_in[1];
  const float* nst_in = (const float*)d_in[2];
  const float* mst_in = (const float*)d_in[3];
  const float* conv_w = (const float*)d_in[4];
  const float* conv_b = (const float*)d_in[5];
  const float* z_w    = (const float*)d_in[6];
  const float* i_w    = (const float*)d_in[7];
  const float* i_b    = (const float*)d_in[8];
  const float* f_w    = (const float*)d_in[9];
  const float* f_b    = (const float*)d_in[10];
  const float* o_w    = (const float*)d_in[11];
  const float* o_b    = (const float*)d_in[12];
  const float* gn_w   = (const float*)d_in[13];
  const float* gn_b   = (const float*)d_in[14];
  const float* out_w  = (const float*)d_in[15];

  char* ws = (char*)d_ws;
  u16* x_bf  = (u16*)(ws);                     // 64 MiB
  u16* xc_bf = (u16*)(ws + 67108864);          // 64 MiB (reused as h_bf)
  u16* w1_bf = (u16*)(ws + 134217728);         // 2 MiB
  u16* zw_bf = (u16*)(ws + 136314880);         // 2 MiB
  u16* ow_bf = (u16*)(ws + 138412032);         // 2 MiB
  u16* wi_bf = (u16*)(ws + 140509184);         // 16 KiB
  u16* wf_bf = (u16*)(ws + 140525568);
  u16* wo_bf = (u16*)(ws + 140541952);
  float* gIv = (float*)(ws + 140558336);       // 1 MiB each
  float* gFv = (float*)(ws + 141606912);
  float* gOv = (float*)(ws + 142655488);       // end ~143.7 MB

  float* outp  = (float*)d_out;
  float* c_out = outp + (size_t)33554432;
  float* n_out = outp + (size_t)67108864;
  float* m_out = outp + (size_t)100663296;

  // 1) conversions
  cvt_f2b<<<dim3((BQ * DD / 4) / 256), 256, 0, stream>>>(x_in, x_bf, BQ * DD / 4);
  cvt_conv<<<dim3((DD * DD) / 256), 256, 0, stream>>>(conv_w, w1_bf);
  cvt_f2b<<<dim3((DD * DD / 4) / 256), 256, 0, stream>>>(z_w, zw_bf, DD * DD / 4);
  cvt_f2b<<<dim3((DD * DD / 4) / 256), 256, 0, stream>>>(out_w, ow_bf, DD * DD / 4);
  cvt_f2b<<<dim3((NHH * DD / 4 + 255) / 256), 256, 0, stream>>>(i_w, wi_bf, NHH * DD / 4);
  cvt_f2b<<<dim3((NHH * DD / 4 + 255) / 256), 256, 0, stream>>>(f_w, wf_bf, NHH * DD / 4);
  cvt_f2b<<<dim3((NHH * DD / 4 + 255) / 256), 256, 0, stream>>>(o_w, wo_bf, NHH * DD / 4);

  dim3 gg(DD / 128, BQ / 128);   // (8, 256)

  // 2) x_conv = SiLU(x @ W1^T + conv_b)
  gemm128<1><<<gg, 256, 0, stream>>>(x_bf, w1_bf, BQ, DD, DD, conv_b, xc_bf,
                                     nullptr, nullptr, nullptr, nullptr, nullptr,
                                     nullptr, nullptr, nullptr, nullptr, nullptr);
  // 3) gates
  gates_k<<<dim3(BQ / 4), 256, 0, stream>>>(x_bf, xc_bf, wi_bf, wf_bf, wo_bf,
                                            i_b, f_b, o_b, mst_in, gIv, gFv, gOv, m_out);
  // 4) z GEMM + gating + per-head LN -> c_new, n_new, h_bf (reuses xc_bf buf)
  gemm128<2><<<gg, 256, 0, stream>>>(x_bf, zw_bf, BQ, DD, DD, nullptr, xc_bf,
                                     cst_in, nst_in, gIv, gFv, gOv, gn_w, gn_b,
                                     c_out, n_out, nullptr);
  // 5) out = h_norm @ out_w^T
  gemm128<3><<<gg, 256, 0, stream>>>(xc_bf, ow_bf, BQ, DD, DD, nullptr, nullptr,
                                     nullptr, nullptr, nullptr, nullptr, nullptr,
                                     nullptr, nullptr, nullptr, nullptr, outp);
}